// Round 4
// baseline (1352.558 us; speedup 1.0000x reference)
//
#include <hip/hip_runtime.h>
#include <hip/hip_bf16.h>
#include <math.h>

static inline size_t align_up(size_t x, size_t a) { return (x + a - 1) / a * a; }

typedef short bf16x8 __attribute__((ext_vector_type(8)));
typedef float f32x4 __attribute__((ext_vector_type(4)));

// ---------------- CSR build ----------------

__global__ void hist_kernel(const int* __restrict__ dst, int* __restrict__ cnt, int e) {
  int i = blockIdx.x * blockDim.x + threadIdx.x;
  if (i < e) atomicAdd(&cnt[dst[i]], 1);
}

__global__ __launch_bounds__(256) void scanA_kernel(const int* __restrict__ cnt,
                                                    int* __restrict__ excl,
                                                    int* __restrict__ bsum, int n) {
  __shared__ int sm[256];
  int gi = blockIdx.x * 256 + threadIdx.x;
  int v = (gi < n) ? cnt[gi] : 0;
  sm[threadIdx.x] = v;
  __syncthreads();
  for (int off = 1; off < 256; off <<= 1) {
    int x = (threadIdx.x >= off) ? sm[threadIdx.x - off] : 0;
    __syncthreads();
    sm[threadIdx.x] += x;
    __syncthreads();
  }
  if (gi < n) excl[gi] = sm[threadIdx.x] - v;
  if (threadIdx.x == 255) bsum[blockIdx.x] = sm[255];
}

__global__ __launch_bounds__(512) void scanB_kernel(int* __restrict__ bsum, int nb) {
  __shared__ int sm[512];
  const int t = threadIdx.x;
  int v = (t < nb) ? bsum[t] : 0;
  sm[t] = v;
  __syncthreads();
  for (int off = 1; off < 512; off <<= 1) {
    int x = (t >= off) ? sm[t - off] : 0;
    __syncthreads();
    sm[t] += x;
    __syncthreads();
  }
  if (t < nb) bsum[t] = sm[t] - v;  // exclusive block offsets
}

__global__ void scanC_kernel(int* __restrict__ rowptr, const int* __restrict__ bsum,
                             int n, int e) {
  int gi = blockIdx.x * 256 + threadIdx.x;
  if (gi < n) rowptr[gi] += bsum[blockIdx.x];
  if (gi == 0) rowptr[n] = e;
}

__global__ void dinv_kernel(const int* __restrict__ rowptr, float* __restrict__ dinv, int n) {
  int gi = blockIdx.x * blockDim.x + threadIdx.x;
  if (gi < n) dinv[gi] = rsqrtf((float)(rowptr[gi + 1] - rowptr[gi] + 1));
}

__global__ void fill_kernel(const int* __restrict__ src, const int* __restrict__ dst,
                            const int* __restrict__ rowptr, int* __restrict__ cur,
                            int* __restrict__ ssrc, int e) {
  int i = blockIdx.x * blockDim.x + threadIdx.x;
  if (i < e) {
    int d = dst[i];
    int s = src[i];
    int pos = rowptr[d] + atomicAdd(&cur[d], 1);
    ssrc[pos] = s;
  }
}

// ---------------- split-bf16 helpers ----------------

__device__ __forceinline__ void bf16_split(float x, unsigned short& hi, unsigned short& lo) {
  unsigned u = __float_as_uint(x);
  unsigned r = (u + 0x7fffu + ((u >> 16) & 1u)) & 0xffff0000u;
  hi = (unsigned short)(r >> 16);
  float rem = x - __uint_as_float(r);
  unsigned u2 = __float_as_uint(rem);
  unsigned r2 = u2 + 0x7fffu + ((u2 >> 16) & 1u);
  lo = (unsigned short)(r2 >> 16);
}

// Pack W[K][128] fp32 into MFMA B-fragment order, split hi/lo bf16.
__global__ void wsplit_kernel(const float* __restrict__ W,
                              unsigned short* __restrict__ whi,
                              unsigned short* __restrict__ wlo, int total) {
  int i = blockIdx.x * blockDim.x + threadIdx.x;
  if (i >= total) return;
  int k = i >> 7;
  int n = i & 127;
  unsigned short h, l;
  bf16_split(W[i], h, l);
  size_t idx = ((size_t)(((k >> 5) * 128 + n) * 4 + ((k >> 3) & 3)) << 3) + (k & 7);
  whi[idx] = h;
  wlo[idx] = l;
}

// ---------------- GEMM via split-bf16 MFMA ----------------
// out (sliced [16][n][8]) = A [n][K] @ W[K][128]
// A either row-major (asliced=0, K may be 160 w/ emb concat) or sliced [16][n][8] (asliced=1, K=128)

__global__ __launch_bounds__(256) void gemm_mfma_kernel(
    const float* __restrict__ A, const float* __restrict__ emb,
    const int* __restrict__ drnl,
    const unsigned short* __restrict__ whi, const unsigned short* __restrict__ wlo,
    float* __restrict__ out, int n, int K, int asliced) {
  __shared__ unsigned short Ah[64][168];  // row stride 168 shorts -> 2-way banks (free)
  __shared__ unsigned short Al[64][168];
  const int tid = threadIdx.x;
  const int row0 = blockIdx.x * 64;
  const int Kq = K >> 2;  // float4s per row
  const size_t sstride = (size_t)n * 8;

  for (int i = tid; i < (K << 4); i += 256) {  // 64*K/4 float4s
    const int row = i / Kq;
    const int c4 = i - row * Kq;
    const int col = c4 << 2;
    float4 v = make_float4(0.f, 0.f, 0.f, 0.f);
    const int grow = row0 + row;
    if (grow < n) {
      if (asliced) {
        v = *(const float4*)(A + (size_t)(col >> 3) * sstride + (size_t)grow * 8 + (col & 7));
      } else if (col < 128) {
        v = *(const float4*)(A + (size_t)grow * 128 + col);
      } else {
        v = *(const float4*)(emb + (size_t)drnl[grow] * 32 + (col - 128));
      }
    }
    unsigned short h0, l0, h1, l1, h2, l2, h3, l3;
    bf16_split(v.x, h0, l0);
    bf16_split(v.y, h1, l1);
    bf16_split(v.z, h2, l2);
    bf16_split(v.w, h3, l3);
    ushort4 hv; hv.x = h0; hv.y = h1; hv.z = h2; hv.w = h3;
    ushort4 lv; lv.x = l0; lv.y = l1; lv.z = l2; lv.w = l3;
    *(ushort4*)&Ah[row][col] = hv;
    *(ushort4*)&Al[row][col] = lv;
  }
  __syncthreads();

  const int w = tid >> 6;
  const int l = tid & 63;
  const int r = l & 15;
  const int q = l >> 4;

  f32x4 acc[8];
#pragma unroll
  for (int ct = 0; ct < 8; ++ct) {
    acc[ct][0] = 0.f; acc[ct][1] = 0.f; acc[ct][2] = 0.f; acc[ct][3] = 0.f;
  }

  const int nks = K >> 5;
  for (int ks = 0; ks < nks; ++ks) {
    const int kb = (ks << 5) + (q << 3);
    const bf16x8 ah = *(const bf16x8*)&Ah[(w << 4) + r][kb];
    const bf16x8 al = *(const bf16x8*)&Al[(w << 4) + r][kb];
#pragma unroll
    for (int ct = 0; ct < 8; ++ct) {
      const size_t off = ((size_t)((((ks << 7) + (ct << 4) + r) << 2) + q)) << 3;
      const bf16x8 bh = *(const bf16x8*)(whi + off);
      const bf16x8 bl = *(const bf16x8*)(wlo + off);
      acc[ct] = __builtin_amdgcn_mfma_f32_16x16x32_bf16(ah, bh, acc[ct], 0, 0, 0);
      acc[ct] = __builtin_amdgcn_mfma_f32_16x16x32_bf16(al, bh, acc[ct], 0, 0, 0);
      acc[ct] = __builtin_amdgcn_mfma_f32_16x16x32_bf16(ah, bl, acc[ct], 0, 0, 0);
    }
  }

  // epilogue: write sliced layout; col = ct*16 + r -> slice = col>>3, fl = col&7
#pragma unroll
  for (int ct = 0; ct < 8; ++ct) {
    const int col = (ct << 4) + r;
    float* op = out + (size_t)(col >> 3) * sstride + (col & 7);
#pragma unroll
    for (int j = 0; j < 4; ++j) {
      const int grow = row0 + (w << 4) + (q << 2) + j;
      if (grow < n) op[(size_t)grow * 8] = acc[ct][j];
    }
  }
}

// ---------------- Aggregation: sliced, XCD-pinned ----------------
// hws, zs: [16][n][8].  Block handles 32 nodes of one slice.
// xcd = bid % 8 (round-robin heuristic); slices {xcd, xcd+8} run sequentially per XCD
// so each slice's 3.2 MB gather working set stays resident in that XCD's 4 MB L2.

__global__ __launch_bounds__(256) void agg_sliced_kernel(
    const float* __restrict__ hws, const int* __restrict__ rowptr,
    const int* __restrict__ ssrc, const float* __restrict__ dinv,
    const float* __restrict__ bias, float* __restrict__ zs,
    int n, int nchunks) {
  const int bid = blockIdx.x;
  const int xcd = bid & 7;
  const int j = bid >> 3;
  const int second = (j >= nchunks) ? 1 : 0;
  const int slice = xcd + (second << 3);
  const int chunk = j - second * nchunks;
  const int lane = threadIdx.x & 63;
  const int wv = threadIdx.x >> 6;
  const int fl = lane & 7;
  const int node = chunk * 32 + wv * 8 + (lane >> 3);
  const float* __restrict__ hbase = hws + (size_t)slice * n * 8;
  float acc = 0.f;
  int e = 0, end = 0;
  float dn = 0.f;
  if (node < n) {
    e = rowptr[node];
    end = rowptr[node + 1];
    dn = dinv[node];
  }
  while (__any(e < end)) {
    const bool a0 = e < end;
    const bool a1 = e + 1 < end;
    int s0 = 0, s1 = 0;
    if (a0) s0 = __builtin_nontemporal_load(ssrc + e);
    if (a1) s1 = __builtin_nontemporal_load(ssrc + e + 1);
    if (a0) acc = fmaf(hbase[(size_t)s0 * 8 + fl], dinv[s0] * dn, acc);
    if (a1) acc = fmaf(hbase[(size_t)s1 * 8 + fl], dinv[s1] * dn, acc);
    e += 2;
  }
  if (node < n) {
    acc = fmaf(hbase[(size_t)node * 8 + fl], dn * dn, acc);
    acc += bias[(slice << 3) + fl];
    acc = acc > 0.f ? acc : 0.f;
    __builtin_nontemporal_store(acc, zs + (size_t)slice * n * 8 + (size_t)node * 8 + fl);
  }
}

// ---------------- Pool: segment max over sliced z ----------------

__global__ __launch_bounds__(128) void pool_kernel(const float* __restrict__ zs,
                                                   float* __restrict__ pool, int n, int npg) {
  const int g = blockIdx.x;
  const int c = threadIdx.x;
  const int slice = c >> 3;
  const int fl = c & 7;
  const float* base = zs + (size_t)slice * n * 8 + (size_t)g * npg * 8 + fl;
  float m = -INFINITY;
  for (int r = 0; r < npg; ++r) m = fmaxf(m, base[(size_t)r * 8]);
  pool[(size_t)g * 128 + c] = m;
}

// ---------------- Head MLP: one block (128 threads) per graph ----------------

__global__ __launch_bounds__(128) void final_kernel(
    const float* __restrict__ zs, const float* __restrict__ pool,
    const int* __restrict__ tloc, const int* __restrict__ ptr,
    const float* __restrict__ Wm1, const float* __restrict__ bm1,
    const float* __restrict__ Wm2, const float* __restrict__ bm2,
    float* __restrict__ out, int n) {
  __shared__ float feats[640];
  __shared__ float hid[128];
  const int g = blockIdx.x;
  const int t = threadIdx.x;
  const int base = ptr[g];
  const int u = base + tloc[2 * g];
  const int v = base + tloc[2 * g + 1];
  const int slice = t >> 3;
  const int fl = t & 7;
  const float hu = zs[(size_t)slice * n * 8 + (size_t)u * 8 + fl];
  const float hv = zs[(size_t)slice * n * 8 + (size_t)v * 8 + fl];
  feats[t] = hu;
  feats[128 + t] = hv;
  feats[256 + t] = fabsf(hu - hv);
  feats[384 + t] = hu * hv;
  feats[512 + t] = pool[(size_t)g * 128 + t];
  __syncthreads();
  float acc = bm1[t];
#pragma unroll 8
  for (int k = 0; k < 640; ++k) acc = fmaf(feats[k], Wm1[(size_t)k * 128 + t], acc);
  hid[t] = acc > 0.f ? acc : 0.f;
  __syncthreads();
  if (t < 2) {
    float a = bm2[t];
    for (int j = 0; j < 128; ++j) a = fmaf(hid[j], Wm2[j * 2 + t], a);
    out[g * 2 + t] = a;
  }
}

// ---------------- launch ----------------

extern "C" void kernel_launch(void* const* d_in, const int* in_sizes, int n_in,
                              void* d_out, int out_size, void* d_ws, size_t ws_size,
                              hipStream_t stream) {
  const float* x   = (const float*)d_in[0];
  const float* emb = (const float*)d_in[1];
  const float* W1  = (const float*)d_in[2];
  const float* b1  = (const float*)d_in[3];
  const float* W2  = (const float*)d_in[4];
  const float* b2  = (const float*)d_in[5];
  const float* Wm1 = (const float*)d_in[6];
  const float* bm1 = (const float*)d_in[7];
  const float* Wm2 = (const float*)d_in[8];
  const float* bm2 = (const float*)d_in[9];
  const int* eidx  = (const int*)d_in[10];
  const int* drnl  = (const int*)d_in[11];
  const int* tloc  = (const int*)d_in[13];
  const int* ptr   = (const int*)d_in[14];
  float* out = (float*)d_out;

  const int N = in_sizes[11];
  const int E = in_sizes[10] / 2;
  const int G = in_sizes[13] / 2;
  const int NPG = N / G;
  const int* srcp = eidx;
  const int* dstp = eidx + E;

  char* w = (char*)d_ws;
  size_t o = 0;
  auto alloc = [&](size_t bytes) {
    void* p = w + o;
    o = align_up(o + bytes, 256);
    return p;
  };
  int*   rowptr = (int*)alloc((size_t)(N + 1) * 4);
  int*   cnt    = (int*)alloc((size_t)N * 4);
  int*   bsum   = (int*)alloc(4096);
  float* dinv   = (float*)alloc((size_t)N * 4);
  int*   ssrc   = (int*)alloc((size_t)E * 4);
  float* hws    = (float*)alloc((size_t)N * 128 * 4);  // sliced [16][N][8]
  float* zs     = (float*)alloc((size_t)N * 128 * 4);  // sliced [16][N][8]
  float* poolb  = (float*)alloc((size_t)G * 128 * 4);
  unsigned short* w1hi = (unsigned short*)alloc((size_t)160 * 128 * 2);
  unsigned short* w1lo = (unsigned short*)alloc((size_t)160 * 128 * 2);
  unsigned short* w2hi = (unsigned short*)alloc((size_t)128 * 128 * 2);
  unsigned short* w2lo = (unsigned short*)alloc((size_t)128 * 128 * 2);

  const int nbN = (N + 255) / 256;
  const int nbE = (E + 255) / 256;
  const int nchunks = (N + 31) / 32;

  hipMemsetAsync(cnt, 0, (size_t)N * 4, stream);
  hist_kernel<<<nbE, 256, 0, stream>>>(dstp, cnt, E);
  scanA_kernel<<<nbN, 256, 0, stream>>>(cnt, rowptr, bsum, N);
  scanB_kernel<<<1, 512, 0, stream>>>(bsum, nbN);
  scanC_kernel<<<nbN, 256, 0, stream>>>(rowptr, bsum, N, E);
  dinv_kernel<<<nbN, 256, 0, stream>>>(rowptr, dinv, N);
  hipMemsetAsync(cnt, 0, (size_t)N * 4, stream);
  fill_kernel<<<nbE, 256, 0, stream>>>(srcp, dstp, rowptr, cnt, ssrc, E);

  wsplit_kernel<<<(160 * 128 + 255) / 256, 256, 0, stream>>>(W1, w1hi, w1lo, 160 * 128);
  wsplit_kernel<<<(128 * 128 + 255) / 256, 256, 0, stream>>>(W2, w2hi, w2lo, 128 * 128);

  gemm_mfma_kernel<<<(N + 63) / 64, 256, 0, stream>>>(x, emb, drnl, w1hi, w1lo, hws, N, 160, 0);
  agg_sliced_kernel<<<16 * nchunks, 256, 0, stream>>>(hws, rowptr, ssrc, dinv, b1, zs, N, nchunks);
  gemm_mfma_kernel<<<(N + 63) / 64, 256, 0, stream>>>(zs, emb, drnl, w2hi, w2lo, hws, N, 128, 1);
  agg_sliced_kernel<<<16 * nchunks, 256, 0, stream>>>(hws, rowptr, ssrc, dinv, b2, zs, N, nchunks);
  pool_kernel<<<G, 128, 0, stream>>>(zs, poolb, N, NPG);
  final_kernel<<<G, 128, 0, stream>>>(zs, poolb, tloc, ptr, Wm1, bm1, Wm2, bm2, out, N);
}

// Round 6
// 1149.162 us; speedup vs baseline: 1.1770x; 1.1770x over previous
//
#include <hip/hip_runtime.h>
#include <hip/hip_bf16.h>
#include <math.h>

static inline size_t align_up(size_t x, size_t a) { return (x + a - 1) / a * a; }

typedef short bf16x8 __attribute__((ext_vector_type(8)));
typedef float f32x4 __attribute__((ext_vector_type(4)));

// ---------------- CSR build ----------------

__global__ void hist_kernel(const int* __restrict__ dst, int* __restrict__ cnt, int e) {
  int i = blockIdx.x * blockDim.x + threadIdx.x;
  if (i < e) atomicAdd(&cnt[dst[i]], 1);
}

__global__ __launch_bounds__(256) void scanA_kernel(const int* __restrict__ cnt,
                                                    int* __restrict__ excl,
                                                    int* __restrict__ bsum, int n) {
  __shared__ int sm[256];
  int gi = blockIdx.x * 256 + threadIdx.x;
  int v = (gi < n) ? cnt[gi] : 0;
  sm[threadIdx.x] = v;
  __syncthreads();
  for (int off = 1; off < 256; off <<= 1) {
    int x = (threadIdx.x >= off) ? sm[threadIdx.x - off] : 0;
    __syncthreads();
    sm[threadIdx.x] += x;
    __syncthreads();
  }
  if (gi < n) excl[gi] = sm[threadIdx.x] - v;
  if (threadIdx.x == 255) bsum[blockIdx.x] = sm[255];
}

__global__ __launch_bounds__(512) void scanB_kernel(int* __restrict__ bsum, int nb) {
  __shared__ int sm[512];
  const int t = threadIdx.x;
  int v = (t < nb) ? bsum[t] : 0;
  sm[t] = v;
  __syncthreads();
  for (int off = 1; off < 512; off <<= 1) {
    int x = (t >= off) ? sm[t - off] : 0;
    __syncthreads();
    sm[t] += x;
    __syncthreads();
  }
  if (t < nb) bsum[t] = sm[t] - v;  // exclusive block offsets
}

__global__ void scanC_kernel(int* __restrict__ rowptr, const int* __restrict__ bsum,
                             int n, int e) {
  int gi = blockIdx.x * 256 + threadIdx.x;
  if (gi < n) rowptr[gi] += bsum[blockIdx.x];
  if (gi == 0) rowptr[n] = e;
}

__global__ void dinv_kernel(const int* __restrict__ rowptr, float* __restrict__ dinv, int n) {
  int gi = blockIdx.x * blockDim.x + threadIdx.x;
  if (gi < n) dinv[gi] = rsqrtf((float)(rowptr[gi + 1] - rowptr[gi] + 1));
}

// writes packed edge record {src, wnorm} (as one 64b word) so the agg hot loop
// has a single independent stream + one gather (no dependent dinv gather).
__global__ void fill_kernel(const int* __restrict__ src, const int* __restrict__ dst,
                            const int* __restrict__ rowptr, int* __restrict__ cur,
                            const float* __restrict__ dinv, long long* __restrict__ erec, int e) {
  int i = blockIdx.x * blockDim.x + threadIdx.x;
  if (i < e) {
    int d = dst[i];
    int s = src[i];
    int pos = rowptr[d] + atomicAdd(&cur[d], 1);
    unsigned long long lo = (unsigned int)s;
    unsigned long long hi = (unsigned long long)(unsigned int)__float_as_int(dinv[s] * dinv[d]) << 32;
    erec[pos] = (long long)(hi | lo);
  }
}

// ---------------- split-bf16 helpers ----------------

__device__ __forceinline__ void bf16_split(float x, unsigned short& hi, unsigned short& lo) {
  unsigned u = __float_as_uint(x);
  unsigned r = (u + 0x7fffu + ((u >> 16) & 1u)) & 0xffff0000u;
  hi = (unsigned short)(r >> 16);
  float rem = x - __uint_as_float(r);
  unsigned u2 = __float_as_uint(rem);
  unsigned r2 = u2 + 0x7fffu + ((u2 >> 16) & 1u);
  lo = (unsigned short)(r2 >> 16);
}

// Pack W[K][128] fp32 into MFMA B-fragment order, split hi/lo bf16.
__global__ void wsplit_kernel(const float* __restrict__ W,
                              unsigned short* __restrict__ whi,
                              unsigned short* __restrict__ wlo, int total) {
  int i = blockIdx.x * blockDim.x + threadIdx.x;
  if (i >= total) return;
  int k = i >> 7;
  int n = i & 127;
  unsigned short h, l;
  bf16_split(W[i], h, l);
  size_t idx = ((size_t)(((k >> 5) * 128 + n) * 4 + ((k >> 3) & 3)) << 3) + (k & 7);
  whi[idx] = h;
  wlo[idx] = l;
}

// ---------------- GEMM via split-bf16 MFMA ----------------
// out (sliced [16][n][8]) = A [n][K] @ W[K][128]
// A either row-major (asliced=0, K may be 160 w/ emb concat) or sliced [16][n][8] (asliced=1, K=128)

__global__ __launch_bounds__(256) void gemm_mfma_kernel(
    const float* __restrict__ A, const float* __restrict__ emb,
    const int* __restrict__ drnl,
    const unsigned short* __restrict__ whi, const unsigned short* __restrict__ wlo,
    float* __restrict__ out, int n, int K, int asliced) {
  __shared__ unsigned short Ah[64][168];  // row stride 168 shorts -> 2-way banks (free)
  __shared__ unsigned short Al[64][168];
  const int tid = threadIdx.x;
  const int row0 = blockIdx.x * 64;
  const int Kq = K >> 2;  // float4s per row
  const size_t sstride = (size_t)n * 8;

  for (int i = tid; i < (K << 4); i += 256) {  // 64*K/4 float4s
    const int row = i / Kq;
    const int c4 = i - row * Kq;
    const int col = c4 << 2;
    float4 v = make_float4(0.f, 0.f, 0.f, 0.f);
    const int grow = row0 + row;
    if (grow < n) {
      if (asliced) {
        v = *(const float4*)(A + (size_t)(col >> 3) * sstride + (size_t)grow * 8 + (col & 7));
      } else if (col < 128) {
        v = *(const float4*)(A + (size_t)grow * 128 + col);
      } else {
        v = *(const float4*)(emb + (size_t)drnl[grow] * 32 + (col - 128));
      }
    }
    unsigned short h0, l0, h1, l1, h2, l2, h3, l3;
    bf16_split(v.x, h0, l0);
    bf16_split(v.y, h1, l1);
    bf16_split(v.z, h2, l2);
    bf16_split(v.w, h3, l3);
    ushort4 hv; hv.x = h0; hv.y = h1; hv.z = h2; hv.w = h3;
    ushort4 lv; lv.x = l0; lv.y = l1; lv.z = l2; lv.w = l3;
    *(ushort4*)&Ah[row][col] = hv;
    *(ushort4*)&Al[row][col] = lv;
  }
  __syncthreads();

  const int w = tid >> 6;
  const int l = tid & 63;
  const int r = l & 15;
  const int q = l >> 4;

  f32x4 acc[8];
#pragma unroll
  for (int ct = 0; ct < 8; ++ct) {
    acc[ct][0] = 0.f; acc[ct][1] = 0.f; acc[ct][2] = 0.f; acc[ct][3] = 0.f;
  }

  const int nks = K >> 5;
  for (int ks = 0; ks < nks; ++ks) {
    const int kb = (ks << 5) + (q << 3);
    const bf16x8 ah = *(const bf16x8*)&Ah[(w << 4) + r][kb];
    const bf16x8 al = *(const bf16x8*)&Al[(w << 4) + r][kb];
#pragma unroll
    for (int ct = 0; ct < 8; ++ct) {
      const size_t off = ((size_t)((((ks << 7) + (ct << 4) + r) << 2) + q)) << 3;
      const bf16x8 bh = *(const bf16x8*)(whi + off);
      const bf16x8 bl = *(const bf16x8*)(wlo + off);
      acc[ct] = __builtin_amdgcn_mfma_f32_16x16x32_bf16(ah, bh, acc[ct], 0, 0, 0);
      acc[ct] = __builtin_amdgcn_mfma_f32_16x16x32_bf16(al, bh, acc[ct], 0, 0, 0);
      acc[ct] = __builtin_amdgcn_mfma_f32_16x16x32_bf16(ah, bl, acc[ct], 0, 0, 0);
    }
  }

  // epilogue: write sliced layout; col = ct*16 + r -> slice = col>>3, fl = col&7
#pragma unroll
  for (int ct = 0; ct < 8; ++ct) {
    const int col = (ct << 4) + r;
    float* op = out + (size_t)(col >> 3) * sstride + (col & 7);
#pragma unroll
    for (int j = 0; j < 4; ++j) {
      const int grow = row0 + (w << 4) + (q << 2) + j;
      if (grow < n) op[(size_t)grow * 8] = acc[ct][j];
    }
  }
}

// ---------------- Aggregation: sliced, XCD-pinned, slot-unrolled x8 ----------------
// hws, zs: [16][n][8]. Block = 32 nodes of one slice; lane = (node&7, feature&7).
// xcd = bid % 8; slices {xcd, xcd+8} sequential per XCD so each slice's 3.2 MB
// gather working set stays L2-resident. 8 independent erec->gather->fma chains
// in flight per lane per iteration.

__global__ __launch_bounds__(256) void agg_sliced_kernel(
    const float* __restrict__ hws, const int* __restrict__ rowptr,
    const long long* __restrict__ erec, const float* __restrict__ dinv,
    const float* __restrict__ bias, float* __restrict__ zs,
    int n, int E, int nchunks) {
  const int bid = blockIdx.x;
  const int xcd = bid & 7;
  const int j = bid >> 3;
  const int second = (j >= nchunks) ? 1 : 0;
  const int slice = xcd + (second << 3);
  const int chunk = j - second * nchunks;
  const int lane = threadIdx.x & 63;
  const int wv = threadIdx.x >> 6;
  const int fl = lane & 7;
  const int node = chunk * 32 + wv * 8 + (lane >> 3);
  const float* __restrict__ hbase = hws + (size_t)slice * n * 8;
  float acc = 0.f;
  int e = 0, end = 0;
  float dn = 0.f;
  if (node < n) {
    e = rowptr[node];
    end = rowptr[node + 1];
    dn = dinv[node];
  }
  const int Em1 = E - 1;
  while (__any(e < end)) {
    unsigned long long rec[8];
#pragma unroll
    for (int k = 0; k < 8; ++k) {
      const int idx = (e + k < end) ? (e + k) : Em1;
      rec[k] = (unsigned long long)__builtin_nontemporal_load(erec + idx);
    }
    float v[8];
#pragma unroll
    for (int k = 0; k < 8; ++k) {
      const int s = (int)(unsigned int)rec[k];
      v[k] = hbase[(size_t)s * 8 + fl];
    }
#pragma unroll
    for (int k = 0; k < 8; ++k) {
      const float wn = (e + k < end) ? __int_as_float((int)(rec[k] >> 32)) : 0.f;
      acc = fmaf(v[k], wn, acc);
    }
    e += 8;
  }
  if (node < n) {
    acc = fmaf(hbase[(size_t)node * 8 + fl], dn * dn, acc);
    acc += bias[(slice << 3) + fl];
    acc = acc > 0.f ? acc : 0.f;
    __builtin_nontemporal_store(acc, zs + (size_t)slice * n * 8 + (size_t)node * 8 + fl);
  }
}

// ---------------- Pool: segment max over sliced z ----------------

__global__ __launch_bounds__(128) void pool_kernel(const float* __restrict__ zs,
                                                   float* __restrict__ pool, int n, int npg) {
  const int g = blockIdx.x;
  const int c = threadIdx.x;
  const int slice = c >> 3;
  const int fl = c & 7;
  const float* base = zs + (size_t)slice * n * 8 + (size_t)g * npg * 8 + fl;
  float m = -INFINITY;
  for (int r = 0; r < npg; ++r) m = fmaxf(m, base[(size_t)r * 8]);
  pool[(size_t)g * 128 + c] = m;
}

// ---------------- Head MLP: one block (128 threads) per graph ----------------

__global__ __launch_bounds__(128) void final_kernel(
    const float* __restrict__ zs, const float* __restrict__ pool,
    const int* __restrict__ tloc, const int* __restrict__ ptr,
    const float* __restrict__ Wm1, const float* __restrict__ bm1,
    const float* __restrict__ Wm2, const float* __restrict__ bm2,
    float* __restrict__ out, int n) {
  __shared__ float feats[640];
  __shared__ float hid[128];
  const int g = blockIdx.x;
  const int t = threadIdx.x;
  const int base = ptr[g];
  const int u = base + tloc[2 * g];
  const int v = base + tloc[2 * g + 1];
  const int slice = t >> 3;
  const int fl = t & 7;
  const float hu = zs[(size_t)slice * n * 8 + (size_t)u * 8 + fl];
  const float hv = zs[(size_t)slice * n * 8 + (size_t)v * 8 + fl];
  feats[t] = hu;
  feats[128 + t] = hv;
  feats[256 + t] = fabsf(hu - hv);
  feats[384 + t] = hu * hv;
  feats[512 + t] = pool[(size_t)g * 128 + t];
  __syncthreads();
  float acc = bm1[t];
#pragma unroll 8
  for (int k = 0; k < 640; ++k) acc = fmaf(feats[k], Wm1[(size_t)k * 128 + t], acc);
  hid[t] = acc > 0.f ? acc : 0.f;
  __syncthreads();
  if (t < 2) {
    float a = bm2[t];
    for (int j = 0; j < 128; ++j) a = fmaf(hid[j], Wm2[j * 2 + t], a);
    out[g * 2 + t] = a;
  }
}

// ---------------- launch ----------------

extern "C" void kernel_launch(void* const* d_in, const int* in_sizes, int n_in,
                              void* d_out, int out_size, void* d_ws, size_t ws_size,
                              hipStream_t stream) {
  const float* x   = (const float*)d_in[0];
  const float* emb = (const float*)d_in[1];
  const float* W1  = (const float*)d_in[2];
  const float* b1  = (const float*)d_in[3];
  const float* W2  = (const float*)d_in[4];
  const float* b2  = (const float*)d_in[5];
  const float* Wm1 = (const float*)d_in[6];
  const float* bm1 = (const float*)d_in[7];
  const float* Wm2 = (const float*)d_in[8];
  const float* bm2 = (const float*)d_in[9];
  const int* eidx  = (const int*)d_in[10];
  const int* drnl  = (const int*)d_in[11];
  const int* tloc  = (const int*)d_in[13];
  const int* ptr   = (const int*)d_in[14];
  float* out = (float*)d_out;

  const int N = in_sizes[11];
  const int E = in_sizes[10] / 2;
  const int G = in_sizes[13] / 2;
  const int NPG = N / G;
  const int* srcp = eidx;
  const int* dstp = eidx + E;

  char* w = (char*)d_ws;
  size_t o = 0;
  auto alloc = [&](size_t bytes) {
    void* p = w + o;
    o = align_up(o + bytes, 256);
    return p;
  };
  int*   rowptr = (int*)alloc((size_t)(N + 1) * 4);
  int*   cnt    = (int*)alloc((size_t)N * 4);
  int*   bsum   = (int*)alloc(4096);
  float* dinv   = (float*)alloc((size_t)N * 4);
  long long* erec = (long long*)alloc((size_t)E * 8);
  float* hws    = (float*)alloc((size_t)N * 128 * 4);  // sliced [16][N][8]
  float* zs     = (float*)alloc((size_t)N * 128 * 4);  // sliced [16][N][8]
  float* poolb  = (float*)alloc((size_t)G * 128 * 4);
  unsigned short* w1hi = (unsigned short*)alloc((size_t)160 * 128 * 2);
  unsigned short* w1lo = (unsigned short*)alloc((size_t)160 * 128 * 2);
  unsigned short* w2hi = (unsigned short*)alloc((size_t)128 * 128 * 2);
  unsigned short* w2lo = (unsigned short*)alloc((size_t)128 * 128 * 2);

  const int nbN = (N + 255) / 256;
  const int nbE = (E + 255) / 256;
  const int nchunks = (N + 31) / 32;

  hipMemsetAsync(cnt, 0, (size_t)N * 4, stream);
  hist_kernel<<<nbE, 256, 0, stream>>>(dstp, cnt, E);
  scanA_kernel<<<nbN, 256, 0, stream>>>(cnt, rowptr, bsum, N);
  scanB_kernel<<<1, 512, 0, stream>>>(bsum, nbN);
  scanC_kernel<<<nbN, 256, 0, stream>>>(rowptr, bsum, N, E);
  dinv_kernel<<<nbN, 256, 0, stream>>>(rowptr, dinv, N);
  hipMemsetAsync(cnt, 0, (size_t)N * 4, stream);
  fill_kernel<<<nbE, 256, 0, stream>>>(srcp, dstp, rowptr, cnt, dinv, erec, E);

  wsplit_kernel<<<(160 * 128 + 255) / 256, 256, 0, stream>>>(W1, w1hi, w1lo, 160 * 128);
  wsplit_kernel<<<(128 * 128 + 255) / 256, 256, 0, stream>>>(W2, w2hi, w2lo, 128 * 128);

  gemm_mfma_kernel<<<(N + 63) / 64, 256, 0, stream>>>(x, emb, drnl, w1hi, w1lo, hws, N, 160, 0);
  agg_sliced_kernel<<<16 * nchunks, 256, 0, stream>>>(hws, rowptr, erec, dinv, b1, zs, N, E, nchunks);
  gemm_mfma_kernel<<<(N + 63) / 64, 256, 0, stream>>>(zs, emb, drnl, w2hi, w2lo, hws, N, 128, 1);
  agg_sliced_kernel<<<16 * nchunks, 256, 0, stream>>>(hws, rowptr, erec, dinv, b2, zs, N, E, nchunks);
  pool_kernel<<<G, 128, 0, stream>>>(zs, poolb, N, NPG);
  final_kernel<<<G, 128, 0, stream>>>(zs, poolb, tloc, ptr, Wm1, bm1, Wm2, bm2, out, N);
}

// Round 7
// 435.594 us; speedup vs baseline: 3.1051x; 2.6381x over previous
//
#include <hip/hip_runtime.h>
#include <hip/hip_bf16.h>
#include <math.h>

static inline size_t align_up(size_t x, size_t a) { return (x + a - 1) / a * a; }

typedef short bf16x8 __attribute__((ext_vector_type(8)));
typedef float f32x4 __attribute__((ext_vector_type(4)));
typedef unsigned short u16x8 __attribute__((ext_vector_type(8)));

// ---------------- CSR build ----------------

__global__ void hist_kernel(const int* __restrict__ dst, int* __restrict__ cnt, int e) {
  int i = blockIdx.x * blockDim.x + threadIdx.x;
  if (i < e) atomicAdd(&cnt[dst[i]], 1);
}

__global__ __launch_bounds__(256) void scanA_kernel(const int* __restrict__ cnt,
                                                    int* __restrict__ excl,
                                                    int* __restrict__ bsum, int n) {
  __shared__ int sm[256];
  int gi = blockIdx.x * 256 + threadIdx.x;
  int v = (gi < n) ? cnt[gi] : 0;
  sm[threadIdx.x] = v;
  __syncthreads();
  for (int off = 1; off < 256; off <<= 1) {
    int x = (threadIdx.x >= off) ? sm[threadIdx.x - off] : 0;
    __syncthreads();
    sm[threadIdx.x] += x;
    __syncthreads();
  }
  if (gi < n) excl[gi] = sm[threadIdx.x] - v;
  if (threadIdx.x == 255) bsum[blockIdx.x] = sm[255];
}

__global__ __launch_bounds__(512) void scanB_kernel(int* __restrict__ bsum, int nb) {
  __shared__ int sm[512];
  const int t = threadIdx.x;
  int v = (t < nb) ? bsum[t] : 0;
  sm[t] = v;
  __syncthreads();
  for (int off = 1; off < 512; off <<= 1) {
    int x = (t >= off) ? sm[t - off] : 0;
    __syncthreads();
    sm[t] += x;
    __syncthreads();
  }
  if (t < nb) bsum[t] = sm[t] - v;  // exclusive block offsets
}

// rowptr finalize + dinv from counts (cnt still holds per-node degree here)
__global__ void scanC_dinv_kernel(int* __restrict__ rowptr, const int* __restrict__ bsum,
                                  const int* __restrict__ cnt, float* __restrict__ dinv,
                                  int n, int e) {
  int gi = blockIdx.x * 256 + threadIdx.x;
  if (gi < n) {
    rowptr[gi] += bsum[blockIdx.x];
    dinv[gi] = rsqrtf((float)(cnt[gi] + 1));
  }
  if (gi == 0) rowptr[n] = e;
}

// packs {src, wnorm} into one 64b record; atomicSub on cnt avoids a 2nd memset
__global__ void fill_kernel(const int* __restrict__ src, const int* __restrict__ dst,
                            const int* __restrict__ rowptr, int* __restrict__ cnt,
                            const float* __restrict__ dinv, long long* __restrict__ erec, int e) {
  int i = blockIdx.x * blockDim.x + threadIdx.x;
  if (i < e) {
    int d = dst[i];
    int s = src[i];
    int old = atomicSub(&cnt[d], 1);
    int pos = rowptr[d] + old - 1;
    float wn = dinv[s] * dinv[d];
    unsigned long long rec =
        ((unsigned long long)(unsigned)__float_as_int(wn) << 32) | (unsigned)s;
    erec[pos] = (long long)rec;
  }
}

// ---------------- split-bf16 helpers ----------------

__device__ __forceinline__ void bf16_split(float x, unsigned short& hi, unsigned short& lo) {
  unsigned u = __float_as_uint(x);
  unsigned r = (u + 0x7fffu + ((u >> 16) & 1u)) & 0xffff0000u;
  hi = (unsigned short)(r >> 16);
  float rem = x - __uint_as_float(r);
  unsigned u2 = __float_as_uint(rem);
  unsigned r2 = u2 + 0x7fffu + ((u2 >> 16) & 1u);
  lo = (unsigned short)(r2 >> 16);
}

__device__ __forceinline__ unsigned short bf16_rtn(float x) {
  unsigned u = __float_as_uint(x);
  return (unsigned short)((u + 0x7fffu + ((u >> 16) & 1u)) >> 16);
}

// Pack both weight matrices into MFMA B-fragment order, split hi/lo bf16.
__global__ void wsplit_kernel(const float* __restrict__ W1, const float* __restrict__ W2,
                              unsigned short* __restrict__ w1hi, unsigned short* __restrict__ w1lo,
                              unsigned short* __restrict__ w2hi, unsigned short* __restrict__ w2lo) {
  int i = blockIdx.x * blockDim.x + threadIdx.x;
  const int t1 = 160 * 128;
  const int t2 = 128 * 128;
  const float* W;
  unsigned short *whi, *wlo;
  if (i < t1) {
    W = W1; whi = w1hi; wlo = w1lo;
  } else {
    i -= t1;
    if (i >= t2) return;
    W = W2; whi = w2hi; wlo = w2lo;
  }
  int k = i >> 7;
  int n = i & 127;
  unsigned short h, l;
  bf16_split(W[i], h, l);
  size_t idx = ((size_t)(((k >> 5) * 128 + n) * 4 + ((k >> 3) & 3)) << 3) + (k & 7);
  whi[idx] = h;
  wlo[idx] = l;
}

// ---------------- GEMM via split-bf16 MFMA, bf16 output ----------------
// outb (bf16 [n][128]) = A[n][K] @ W[K][128];  A row-major fp32 (K=160: concat x|emb[drnl])

__global__ __launch_bounds__(256) void gemm_mfma_kernel(
    const float* __restrict__ A, const float* __restrict__ emb,
    const int* __restrict__ drnl,
    const unsigned short* __restrict__ whi, const unsigned short* __restrict__ wlo,
    unsigned short* __restrict__ outb, int n, int K) {
  __shared__ unsigned short Ah[64][168];  // row stride 168 shorts -> benign banking
  __shared__ unsigned short Al[64][168];
  const int tid = threadIdx.x;
  const int row0 = blockIdx.x * 64;
  const int Kq = K >> 2;  // float4s per row

  for (int i = tid; i < (K << 4); i += 256) {  // 64*K/4 float4s
    const int row = i / Kq;
    const int c4 = i - row * Kq;
    const int col = c4 << 2;
    float4 v = make_float4(0.f, 0.f, 0.f, 0.f);
    const int grow = row0 + row;
    if (grow < n) {
      if (col < 128) v = *(const float4*)(A + (size_t)grow * 128 + col);
      else v = *(const float4*)(emb + (size_t)drnl[grow] * 32 + (col - 128));
    }
    unsigned short h0, l0, h1, l1, h2, l2, h3, l3;
    bf16_split(v.x, h0, l0);
    bf16_split(v.y, h1, l1);
    bf16_split(v.z, h2, l2);
    bf16_split(v.w, h3, l3);
    ushort4 hv; hv.x = h0; hv.y = h1; hv.z = h2; hv.w = h3;
    ushort4 lv; lv.x = l0; lv.y = l1; lv.z = l2; lv.w = l3;
    *(ushort4*)&Ah[row][col] = hv;
    *(ushort4*)&Al[row][col] = lv;
  }
  __syncthreads();

  const int w = tid >> 6;
  const int l = tid & 63;
  const int r = l & 15;
  const int q = l >> 4;

  f32x4 acc[8];
#pragma unroll
  for (int ct = 0; ct < 8; ++ct) {
    acc[ct][0] = 0.f; acc[ct][1] = 0.f; acc[ct][2] = 0.f; acc[ct][3] = 0.f;
  }

  const int nks = K >> 5;
  for (int ks = 0; ks < nks; ++ks) {
    const int kb = (ks << 5) + (q << 3);
    const bf16x8 ah = *(const bf16x8*)&Ah[(w << 4) + r][kb];
    const bf16x8 al = *(const bf16x8*)&Al[(w << 4) + r][kb];
#pragma unroll
    for (int ct = 0; ct < 8; ++ct) {
      const size_t off = ((size_t)((((ks << 7) + (ct << 4) + r) << 2) + q)) << 3;
      const bf16x8 bh = *(const bf16x8*)(whi + off);
      const bf16x8 bl = *(const bf16x8*)(wlo + off);
      acc[ct] = __builtin_amdgcn_mfma_f32_16x16x32_bf16(ah, bh, acc[ct], 0, 0, 0);
      acc[ct] = __builtin_amdgcn_mfma_f32_16x16x32_bf16(al, bh, acc[ct], 0, 0, 0);
      acc[ct] = __builtin_amdgcn_mfma_f32_16x16x32_bf16(ah, bl, acc[ct], 0, 0, 0);
    }
  }

  // epilogue: bf16 round, transpose through LDS (reuse Ah), coalesced 16B stores
  __syncthreads();
#pragma unroll
  for (int ct = 0; ct < 8; ++ct) {
    const int col = (ct << 4) + r;
#pragma unroll
    for (int j = 0; j < 4; ++j) {
      const int row = (w << 4) + (q << 2) + j;
      Ah[row][col] = bf16_rtn(acc[ct][j]);
    }
  }
  __syncthreads();
#pragma unroll
  for (int p = 0; p < 4; ++p) {
    const int row = p * 16 + (tid >> 4);
    const int grow = row0 + row;
    if (grow < n) {
      const int c8 = (tid & 15) * 8;
      *(u16x8*)(outb + (size_t)grow * 128 + c8) = *(const u16x8*)&Ah[row][c8];
    }
  }
}

// ---------------- Aggregation: one wave per node, bf16 gather table ----------------
// hwb: bf16 [n][128] (= [n][64] dwords). lane holds features {2*lane, 2*lane+1}.
// erec wave-uniform -> scalar loads; 4 independent 256B gathers in flight.

__global__ __launch_bounds__(256) void agg_kernel(
    const unsigned* __restrict__ hwb, const int* __restrict__ rowptr,
    const long long* __restrict__ erec, const float* __restrict__ dinv,
    const float* __restrict__ bias, float* __restrict__ z, int n) {
  const int widx = (blockIdx.x * blockDim.x + threadIdx.x) >> 6;
  if (widx >= n) return;
  const int wid = __builtin_amdgcn_readfirstlane(widx);
  const int lane = threadIdx.x & 63;
  const int start = rowptr[wid];
  const int end = rowptr[wid + 1];
  float ax = 0.f, ay = 0.f;
  int e = start;
  for (; e + 4 <= end; e += 4) {
    const unsigned long long r0 = (unsigned long long)erec[e + 0];
    const unsigned long long r1 = (unsigned long long)erec[e + 1];
    const unsigned long long r2 = (unsigned long long)erec[e + 2];
    const unsigned long long r3 = (unsigned long long)erec[e + 3];
    const unsigned u0 = hwb[((size_t)(unsigned)r0) * 64 + lane];
    const unsigned u1 = hwb[((size_t)(unsigned)r1) * 64 + lane];
    const unsigned u2 = hwb[((size_t)(unsigned)r2) * 64 + lane];
    const unsigned u3 = hwb[((size_t)(unsigned)r3) * 64 + lane];
    const float w0 = __uint_as_float((unsigned)(r0 >> 32));
    const float w1 = __uint_as_float((unsigned)(r1 >> 32));
    const float w2 = __uint_as_float((unsigned)(r2 >> 32));
    const float w3 = __uint_as_float((unsigned)(r3 >> 32));
    ax = fmaf(__uint_as_float(u0 << 16), w0, ax);
    ay = fmaf(__uint_as_float(u0 & 0xffff0000u), w0, ay);
    ax = fmaf(__uint_as_float(u1 << 16), w1, ax);
    ay = fmaf(__uint_as_float(u1 & 0xffff0000u), w1, ay);
    ax = fmaf(__uint_as_float(u2 << 16), w2, ax);
    ay = fmaf(__uint_as_float(u2 & 0xffff0000u), w2, ay);
    ax = fmaf(__uint_as_float(u3 << 16), w3, ax);
    ay = fmaf(__uint_as_float(u3 & 0xffff0000u), w3, ay);
  }
  for (; e < end; ++e) {
    const unsigned long long r0 = (unsigned long long)erec[e];
    const unsigned u0 = hwb[((size_t)(unsigned)r0) * 64 + lane];
    const float w0 = __uint_as_float((unsigned)(r0 >> 32));
    ax = fmaf(__uint_as_float(u0 << 16), w0, ax);
    ay = fmaf(__uint_as_float(u0 & 0xffff0000u), w0, ay);
  }
  const float dn = dinv[wid];
  const float sw = dn * dn;
  const unsigned us = hwb[(size_t)wid * 64 + lane];
  ax = fmaf(__uint_as_float(us << 16), sw, ax);
  ay = fmaf(__uint_as_float(us & 0xffff0000u), sw, ay);
  const float2 bb = ((const float2*)bias)[lane];
  float ox = ax + bb.x, oy = ay + bb.y;
  float2 o;
  o.x = ox > 0.f ? ox : 0.f;
  o.y = oy > 0.f ? oy : 0.f;
  ((float2*)z)[(size_t)wid * 64 + lane] = o;
}

// ---------------- Head: fused segment-max pool + MLP, one block per graph ----------------

__global__ __launch_bounds__(128) void final_kernel(
    const float* __restrict__ z, const int* __restrict__ tloc,
    const int* __restrict__ ptr,
    const float* __restrict__ Wm1, const float* __restrict__ bm1,
    const float* __restrict__ Wm2, const float* __restrict__ bm2,
    float* __restrict__ out, int npg) {
  __shared__ float feats[640];
  __shared__ float hid[128];
  const int g = blockIdx.x;
  const int t = threadIdx.x;
  const float* zb = z + (size_t)g * npg * 128;
  float m = -INFINITY;
  for (int r = 0; r < npg; ++r) m = fmaxf(m, zb[(size_t)r * 128 + t]);
  feats[512 + t] = m;
  const int base = ptr[g];
  const int u = base + tloc[2 * g];
  const int v = base + tloc[2 * g + 1];
  const float hu = z[(size_t)u * 128 + t];
  const float hv = z[(size_t)v * 128 + t];
  feats[t] = hu;
  feats[128 + t] = hv;
  feats[256 + t] = fabsf(hu - hv);
  feats[384 + t] = hu * hv;
  __syncthreads();
  float acc = bm1[t];
#pragma unroll 8
  for (int k = 0; k < 640; ++k) acc = fmaf(feats[k], Wm1[(size_t)k * 128 + t], acc);
  hid[t] = acc > 0.f ? acc : 0.f;
  __syncthreads();
  if (t < 2) {
    float a = bm2[t];
    for (int j = 0; j < 128; ++j) a = fmaf(hid[j], Wm2[j * 2 + t], a);
    out[g * 2 + t] = a;
  }
}

// ---------------- launch ----------------

extern "C" void kernel_launch(void* const* d_in, const int* in_sizes, int n_in,
                              void* d_out, int out_size, void* d_ws, size_t ws_size,
                              hipStream_t stream) {
  const float* x   = (const float*)d_in[0];
  const float* emb = (const float*)d_in[1];
  const float* W1  = (const float*)d_in[2];
  const float* b1  = (const float*)d_in[3];
  const float* W2  = (const float*)d_in[4];
  const float* b2  = (const float*)d_in[5];
  const float* Wm1 = (const float*)d_in[6];
  const float* bm1 = (const float*)d_in[7];
  const float* Wm2 = (const float*)d_in[8];
  const float* bm2 = (const float*)d_in[9];
  const int* eidx  = (const int*)d_in[10];
  const int* drnl  = (const int*)d_in[11];
  const int* tloc  = (const int*)d_in[13];
  const int* ptr   = (const int*)d_in[14];
  float* out = (float*)d_out;

  const int N = in_sizes[11];
  const int E = in_sizes[10] / 2;
  const int G = in_sizes[13] / 2;
  const int NPG = N / G;
  const int* srcp = eidx;
  const int* dstp = eidx + E;

  char* w = (char*)d_ws;
  size_t o = 0;
  auto alloc = [&](size_t bytes) {
    void* p = w + o;
    o = align_up(o + bytes, 256);
    return p;
  };
  int*   rowptr = (int*)alloc((size_t)(N + 1) * 4);
  int*   cnt    = (int*)alloc((size_t)N * 4);
  int*   bsum   = (int*)alloc(4096);
  float* dinv   = (float*)alloc((size_t)N * 4);
  long long* erec = (long long*)alloc((size_t)E * 8);
  unsigned short* hwb = (unsigned short*)alloc((size_t)N * 128 * 2);  // bf16 [N][128]
  float* z      = (float*)alloc((size_t)N * 128 * 4);
  unsigned short* w1hi = (unsigned short*)alloc((size_t)160 * 128 * 2);
  unsigned short* w1lo = (unsigned short*)alloc((size_t)160 * 128 * 2);
  unsigned short* w2hi = (unsigned short*)alloc((size_t)128 * 128 * 2);
  unsigned short* w2lo = (unsigned short*)alloc((size_t)128 * 128 * 2);

  const int nbN = (N + 255) / 256;
  const int nbE = (E + 255) / 256;

  hipMemsetAsync(cnt, 0, (size_t)N * 4, stream);
  hist_kernel<<<nbE, 256, 0, stream>>>(dstp, cnt, E);
  scanA_kernel<<<nbN, 256, 0, stream>>>(cnt, rowptr, bsum, N);
  scanB_kernel<<<1, 512, 0, stream>>>(bsum, nbN);
  scanC_dinv_kernel<<<nbN, 256, 0, stream>>>(rowptr, bsum, cnt, dinv, N, E);
  fill_kernel<<<nbE, 256, 0, stream>>>(srcp, dstp, rowptr, cnt, dinv, erec, E);

  wsplit_kernel<<<(160 * 128 + 128 * 128 + 255) / 256, 256, 0, stream>>>(
      W1, W2, w1hi, w1lo, w2hi, w2lo);

  gemm_mfma_kernel<<<(N + 63) / 64, 256, 0, stream>>>(x, emb, drnl, w1hi, w1lo, hwb, N, 160);
  agg_kernel<<<(N * 64 + 255) / 256, 256, 0, stream>>>((const unsigned*)hwb, rowptr, erec, dinv, b1, z, N);
  gemm_mfma_kernel<<<(N + 63) / 64, 256, 0, stream>>>(z, emb, drnl, w2hi, w2lo, hwb, N, 128);
  agg_kernel<<<(N * 64 + 255) / 256, 256, 0, stream>>>((const unsigned*)hwb, rowptr, erec, dinv, b2, z, N);
  final_kernel<<<G, 128, 0, stream>>>(z, tloc, ptr, Wm1, bm1, Wm2, bm2, out, NPG);
}

// Round 8
// 369.302 us; speedup vs baseline: 3.6625x; 1.1795x over previous
//
#include <hip/hip_runtime.h>
#include <hip/hip_bf16.h>
#include <math.h>

static inline size_t align_up(size_t x, size_t a) { return (x + a - 1) / a * a; }

typedef short bf16x8 __attribute__((ext_vector_type(8)));
typedef float f32x4 __attribute__((ext_vector_type(4)));
typedef unsigned short u16x8 __attribute__((ext_vector_type(8)));

// ---------------- CSR build ----------------

__global__ void hist_kernel(const int* __restrict__ dst, int* __restrict__ cnt, int e) {
  int i = blockIdx.x * blockDim.x + threadIdx.x;
  if (i < e) atomicAdd(&cnt[dst[i]], 1);
}

__global__ __launch_bounds__(256) void scanA_kernel(const int* __restrict__ cnt,
                                                    int* __restrict__ excl,
                                                    int* __restrict__ bsum, int n) {
  __shared__ int sm[256];
  int gi = blockIdx.x * 256 + threadIdx.x;
  int v = (gi < n) ? cnt[gi] : 0;
  sm[threadIdx.x] = v;
  __syncthreads();
  for (int off = 1; off < 256; off <<= 1) {
    int x = (threadIdx.x >= off) ? sm[threadIdx.x - off] : 0;
    __syncthreads();
    sm[threadIdx.x] += x;
    __syncthreads();
  }
  if (gi < n) excl[gi] = sm[threadIdx.x] - v;
  if (threadIdx.x == 255) bsum[blockIdx.x] = sm[255];
}

__global__ __launch_bounds__(512) void scanB_kernel(int* __restrict__ bsum, int nb) {
  __shared__ int sm[512];
  const int t = threadIdx.x;
  int v = (t < nb) ? bsum[t] : 0;
  sm[t] = v;
  __syncthreads();
  for (int off = 1; off < 512; off <<= 1) {
    int x = (t >= off) ? sm[t - off] : 0;
    __syncthreads();
    sm[t] += x;
    __syncthreads();
  }
  if (t < nb) bsum[t] = sm[t] - v;  // exclusive block offsets
}

// rowptr finalize + dinv from counts (cnt still holds per-node degree here)
__global__ void scanC_dinv_kernel(int* __restrict__ rowptr, const int* __restrict__ bsum,
                                  const int* __restrict__ cnt, float* __restrict__ dinv,
                                  int n, int e) {
  int gi = blockIdx.x * 256 + threadIdx.x;
  if (gi < n) {
    rowptr[gi] += bsum[blockIdx.x];
    dinv[gi] = rsqrtf((float)(cnt[gi] + 1));
  }
  if (gi == 0) rowptr[n] = e;
}

// packs {src, wnorm} into one 64b record; atomicSub on cnt avoids a 2nd memset
__global__ void fill_kernel(const int* __restrict__ src, const int* __restrict__ dst,
                            const int* __restrict__ rowptr, int* __restrict__ cnt,
                            const float* __restrict__ dinv, long long* __restrict__ erec, int e) {
  int i = blockIdx.x * blockDim.x + threadIdx.x;
  if (i < e) {
    int d = dst[i];
    int s = src[i];
    int old = atomicSub(&cnt[d], 1);
    int pos = rowptr[d] + old - 1;
    float wn = dinv[s] * dinv[d];
    unsigned long long rec =
        ((unsigned long long)(unsigned)__float_as_int(wn) << 32) | (unsigned)s;
    erec[pos] = (long long)rec;
  }
}

// ---------------- split-bf16 helpers ----------------

__device__ __forceinline__ void bf16_split(float x, unsigned short& hi, unsigned short& lo) {
  unsigned u = __float_as_uint(x);
  unsigned r = (u + 0x7fffu + ((u >> 16) & 1u)) & 0xffff0000u;
  hi = (unsigned short)(r >> 16);
  float rem = x - __uint_as_float(r);
  unsigned u2 = __float_as_uint(rem);
  unsigned r2 = u2 + 0x7fffu + ((u2 >> 16) & 1u);
  lo = (unsigned short)(r2 >> 16);
}

__device__ __forceinline__ unsigned short bf16_rtn(float x) {
  unsigned u = __float_as_uint(x);
  return (unsigned short)((u + 0x7fffu + ((u >> 16) & 1u)) >> 16);
}

// Pack both weight matrices into MFMA B-fragment order, split hi/lo bf16.
// Entry (k,n): flat = (((k>>5)*128 + n)*4 + ((k>>3)&3))*8 + (k&7)
//   -> per K-step ks: contiguous 4096-short block (8KB), ideal for LDS staging.
__global__ void wsplit_kernel(const float* __restrict__ W1, const float* __restrict__ W2,
                              unsigned short* __restrict__ w1hi, unsigned short* __restrict__ w1lo,
                              unsigned short* __restrict__ w2hi, unsigned short* __restrict__ w2lo) {
  int i = blockIdx.x * blockDim.x + threadIdx.x;
  const int t1 = 160 * 128;
  const int t2 = 128 * 128;
  const float* W;
  unsigned short *whi, *wlo;
  if (i < t1) {
    W = W1; whi = w1hi; wlo = w1lo;
  } else {
    i -= t1;
    if (i >= t2) return;
    W = W2; whi = w2hi; wlo = w2lo;
  }
  int k = i >> 7;
  int n = i & 127;
  unsigned short h, l;
  bf16_split(W[i], h, l);
  size_t idx = ((size_t)(((k >> 5) * 128 + n) * 4 + ((k >> 3) & 3)) << 3) + (k & 7);
  whi[idx] = h;
  wlo[idx] = l;
}

// ---------------- GEMM via split-bf16 MFMA: B in LDS, A in registers ----------------
// outb (bf16 [n][128]) = A[n][K] @ W[K][128]; A row-major fp32 (K=160: concat x|emb[drnl]).
// 512 threads = 8 waves x 16 rows = 128 rows/block. Per K-step (BK=32): stage 16KB of
// B fragments (hi+lo) into LDS (bulk-coalesced, issued during previous compute);
// A fragment loaded straight to regs (32B/lane) and split in-register.

__global__ __launch_bounds__(512) void gemm_mfma_kernel(
    const float* __restrict__ A, const float* __restrict__ emb,
    const int* __restrict__ drnl,
    const unsigned short* __restrict__ whi, const unsigned short* __restrict__ wlo,
    unsigned short* __restrict__ outb, int n, int K) {
  // B tile: [0..4095]=hi, [4096..8191]=lo. Epilogue reuses as [128][132] transpose buf.
  __shared__ unsigned short smem[16896];  // 33792 B
  const int tid = threadIdx.x;
  const int row0 = blockIdx.x * 128;
  const int w = tid >> 6;
  const int l = tid & 63;
  const int r = l & 15;
  const int q = l >> 4;
  const int grow = row0 + (w << 4) + r;   // this lane's A row
  const bool rowok = grow < n;
  const int nks = K >> 5;

  int embrow = 0;
  if (K > 128 && rowok) embrow = drnl[grow];

  f32x4 acc[8];
#pragma unroll
  for (int ct = 0; ct < 8; ++ct) {
    acc[ct][0] = 0.f; acc[ct][1] = 0.f; acc[ct][2] = 0.f; acc[ct][3] = 0.f;
  }

  // B staging regs (issue-early / write-late)
  u16x8 bst_h = {0,0,0,0,0,0,0,0}, bst_l = {0,0,0,0,0,0,0,0};
  bst_h = *(const u16x8*)(whi + (size_t)tid * 8);
  bst_l = *(const u16x8*)(wlo + (size_t)tid * 8);

  for (int ks = 0; ks < nks; ++ks) {
    // A fragment for this K-step -> registers, split to hi/lo bf16
    const int k0 = (ks << 5) + (q << 3);
    float4 a0 = make_float4(0.f, 0.f, 0.f, 0.f), a1 = a0;
    if (rowok) {
      if (k0 < 128) {
        const float* ap = A + (size_t)grow * 128 + k0;
        a0 = *(const float4*)ap;
        a1 = *(const float4*)(ap + 4);
      } else {
        const float* ep = emb + (size_t)embrow * 32 + (k0 - 128);
        a0 = *(const float4*)ep;
        a1 = *(const float4*)(ep + 4);
      }
    }
    bf16x8 ah, al;
    {
      unsigned short h, lo_;
      bf16_split(a0.x, h, lo_); ah[0] = (short)h; al[0] = (short)lo_;
      bf16_split(a0.y, h, lo_); ah[1] = (short)h; al[1] = (short)lo_;
      bf16_split(a0.z, h, lo_); ah[2] = (short)h; al[2] = (short)lo_;
      bf16_split(a0.w, h, lo_); ah[3] = (short)h; al[3] = (short)lo_;
      bf16_split(a1.x, h, lo_); ah[4] = (short)h; al[4] = (short)lo_;
      bf16_split(a1.y, h, lo_); ah[5] = (short)h; al[5] = (short)lo_;
      bf16_split(a1.z, h, lo_); ah[6] = (short)h; al[6] = (short)lo_;
      bf16_split(a1.w, h, lo_); ah[7] = (short)h; al[7] = (short)lo_;
    }

    if (ks) __syncthreads();               // previous compute done reading B tile
    *(u16x8*)&smem[tid * 8] = bst_h;       // publish this K-step's B tile
    *(u16x8*)&smem[4096 + tid * 8] = bst_l;
    __syncthreads();

    if (ks + 1 < nks) {                    // prefetch next tile during compute
      bst_h = *(const u16x8*)(whi + (size_t)(ks + 1) * 4096 + (size_t)tid * 8);
      bst_l = *(const u16x8*)(wlo + (size_t)(ks + 1) * 4096 + (size_t)tid * 8);
    }

#pragma unroll
    for (int ct = 0; ct < 8; ++ct) {
      const int boff = ((ct << 4) + r) * 32 + (q << 3);  // contiguous 1KB per wave: conflict-free
      const bf16x8 bh = *(const bf16x8*)&smem[boff];
      const bf16x8 bl = *(const bf16x8*)&smem[4096 + boff];
      acc[ct] = __builtin_amdgcn_mfma_f32_16x16x32_bf16(ah, bh, acc[ct], 0, 0, 0);
      acc[ct] = __builtin_amdgcn_mfma_f32_16x16x32_bf16(al, bh, acc[ct], 0, 0, 0);
      acc[ct] = __builtin_amdgcn_mfma_f32_16x16x32_bf16(ah, bl, acc[ct], 0, 0, 0);
    }
  }

  // epilogue: bf16 round -> LDS transpose ([128][132] pad kills 4-way write conflict)
  // -> coalesced 16B stores
  __syncthreads();
#pragma unroll
  for (int ct = 0; ct < 8; ++ct) {
    const int col = (ct << 4) + r;
#pragma unroll
    for (int j = 0; j < 4; ++j) {
      const int row = (w << 4) + (q << 2) + j;   // C/D: col=lane&15, row=(lane>>4)*4+j
      smem[row * 132 + col] = bf16_rtn(acc[ct][j]);
    }
  }
  __syncthreads();
#pragma unroll
  for (int p = 0; p < 4; ++p) {
    const int idx = p * 512 + tid;
    const int row = idx >> 4;
    const int c8 = (idx & 15) * 8;
    const int gr = row0 + row;
    if (gr < n) {
      u16x8 v = *(const u16x8*)&smem[row * 132 + c8];
      *(u16x8*)(outb + (size_t)gr * 128 + c8) = v;
    }
  }
}

// ---------------- Aggregation: one wave per node, bf16 gather table ----------------

__global__ __launch_bounds__(256) void agg_kernel(
    const unsigned* __restrict__ hwb, const int* __restrict__ rowptr,
    const long long* __restrict__ erec, const float* __restrict__ dinv,
    const float* __restrict__ bias, float* __restrict__ z, int n) {
  const int widx = (blockIdx.x * blockDim.x + threadIdx.x) >> 6;
  if (widx >= n) return;
  const int wid = __builtin_amdgcn_readfirstlane(widx);
  const int lane = threadIdx.x & 63;
  const int start = rowptr[wid];
  const int end = rowptr[wid + 1];
  float ax = 0.f, ay = 0.f;
  int e = start;
  for (; e + 4 <= end; e += 4) {
    const unsigned long long r0 = (unsigned long long)erec[e + 0];
    const unsigned long long r1 = (unsigned long long)erec[e + 1];
    const unsigned long long r2 = (unsigned long long)erec[e + 2];
    const unsigned long long r3 = (unsigned long long)erec[e + 3];
    const unsigned u0 = hwb[((size_t)(unsigned)r0) * 64 + lane];
    const unsigned u1 = hwb[((size_t)(unsigned)r1) * 64 + lane];
    const unsigned u2 = hwb[((size_t)(unsigned)r2) * 64 + lane];
    const unsigned u3 = hwb[((size_t)(unsigned)r3) * 64 + lane];
    const float w0 = __uint_as_float((unsigned)(r0 >> 32));
    const float w1 = __uint_as_float((unsigned)(r1 >> 32));
    const float w2 = __uint_as_float((unsigned)(r2 >> 32));
    const float w3 = __uint_as_float((unsigned)(r3 >> 32));
    ax = fmaf(__uint_as_float(u0 << 16), w0, ax);
    ay = fmaf(__uint_as_float(u0 & 0xffff0000u), w0, ay);
    ax = fmaf(__uint_as_float(u1 << 16), w1, ax);
    ay = fmaf(__uint_as_float(u1 & 0xffff0000u), w1, ay);
    ax = fmaf(__uint_as_float(u2 << 16), w2, ax);
    ay = fmaf(__uint_as_float(u2 & 0xffff0000u), w2, ay);
    ax = fmaf(__uint_as_float(u3 << 16), w3, ax);
    ay = fmaf(__uint_as_float(u3 & 0xffff0000u), w3, ay);
  }
  for (; e < end; ++e) {
    const unsigned long long r0 = (unsigned long long)erec[e];
    const unsigned u0 = hwb[((size_t)(unsigned)r0) * 64 + lane];
    const float w0 = __uint_as_float((unsigned)(r0 >> 32));
    ax = fmaf(__uint_as_float(u0 << 16), w0, ax);
    ay = fmaf(__uint_as_float(u0 & 0xffff0000u), w0, ay);
  }
  const float dn = dinv[wid];
  const float sw = dn * dn;
  const unsigned us = hwb[(size_t)wid * 64 + lane];
  ax = fmaf(__uint_as_float(us << 16), sw, ax);
  ay = fmaf(__uint_as_float(us & 0xffff0000u), sw, ay);
  const float2 bb = ((const float2*)bias)[lane];
  float ox = ax + bb.x, oy = ay + bb.y;
  float2 o;
  o.x = ox > 0.f ? ox : 0.f;
  o.y = oy > 0.f ? oy : 0.f;
  ((float2*)z)[(size_t)wid * 64 + lane] = o;
}

// ---------------- Head: fused segment-max pool + MLP, one block per graph ----------------

__global__ __launch_bounds__(128) void final_kernel(
    const float* __restrict__ z, const int* __restrict__ tloc,
    const int* __restrict__ ptr,
    const float* __restrict__ Wm1, const float* __restrict__ bm1,
    const float* __restrict__ Wm2, const float* __restrict__ bm2,
    float* __restrict__ out, int npg) {
  __shared__ float feats[640];
  __shared__ float hid[128];
  const int g = blockIdx.x;
  const int t = threadIdx.x;
  const float* zb = z + (size_t)g * npg * 128;
  float m = -INFINITY;
  for (int r = 0; r < npg; ++r) m = fmaxf(m, zb[(size_t)r * 128 + t]);
  feats[512 + t] = m;
  const int base = ptr[g];
  const int u = base + tloc[2 * g];
  const int v = base + tloc[2 * g + 1];
  const float hu = z[(size_t)u * 128 + t];
  const float hv = z[(size_t)v * 128 + t];
  feats[t] = hu;
  feats[128 + t] = hv;
  feats[256 + t] = fabsf(hu - hv);
  feats[384 + t] = hu * hv;
  __syncthreads();
  float acc = bm1[t];
#pragma unroll 8
  for (int k = 0; k < 640; ++k) acc = fmaf(feats[k], Wm1[(size_t)k * 128 + t], acc);
  hid[t] = acc > 0.f ? acc : 0.f;
  __syncthreads();
  if (t < 2) {
    float a = bm2[t];
    for (int j = 0; j < 128; ++j) a = fmaf(hid[j], Wm2[j * 2 + t], a);
    out[g * 2 + t] = a;
  }
}

// ---------------- launch ----------------

extern "C" void kernel_launch(void* const* d_in, const int* in_sizes, int n_in,
                              void* d_out, int out_size, void* d_ws, size_t ws_size,
                              hipStream_t stream) {
  const float* x   = (const float*)d_in[0];
  const float* emb = (const float*)d_in[1];
  const float* W1  = (const float*)d_in[2];
  const float* b1  = (const float*)d_in[3];
  const float* W2  = (const float*)d_in[4];
  const float* b2  = (const float*)d_in[5];
  const float* Wm1 = (const float*)d_in[6];
  const float* bm1 = (const float*)d_in[7];
  const float* Wm2 = (const float*)d_in[8];
  const float* bm2 = (const float*)d_in[9];
  const int* eidx  = (const int*)d_in[10];
  const int* drnl  = (const int*)d_in[11];
  const int* tloc  = (const int*)d_in[13];
  const int* ptr   = (const int*)d_in[14];
  float* out = (float*)d_out;

  const int N = in_sizes[11];
  const int E = in_sizes[10] / 2;
  const int G = in_sizes[13] / 2;
  const int NPG = N / G;
  const int* srcp = eidx;
  const int* dstp = eidx + E;

  char* w = (char*)d_ws;
  size_t o = 0;
  auto alloc = [&](size_t bytes) {
    void* p = w + o;
    o = align_up(o + bytes, 256);
    return p;
  };
  int*   rowptr = (int*)alloc((size_t)(N + 1) * 4);
  int*   cnt    = (int*)alloc((size_t)N * 4);
  int*   bsum   = (int*)alloc(4096);
  float* dinv   = (float*)alloc((size_t)N * 4);
  long long* erec = (long long*)alloc((size_t)E * 8);
  unsigned short* hwb = (unsigned short*)alloc((size_t)N * 128 * 2);  // bf16 [N][128]
  float* z      = (float*)alloc((size_t)N * 128 * 4);
  unsigned short* w1hi = (unsigned short*)alloc((size_t)160 * 128 * 2);
  unsigned short* w1lo = (unsigned short*)alloc((size_t)160 * 128 * 2);
  unsigned short* w2hi = (unsigned short*)alloc((size_t)128 * 128 * 2);
  unsigned short* w2lo = (unsigned short*)alloc((size_t)128 * 128 * 2);

  const int nbN = (N + 255) / 256;
  const int nbE = (E + 255) / 256;

  hipMemsetAsync(cnt, 0, (size_t)N * 4, stream);
  hist_kernel<<<nbE, 256, 0, stream>>>(dstp, cnt, E);
  scanA_kernel<<<nbN, 256, 0, stream>>>(cnt, rowptr, bsum, N);
  scanB_kernel<<<1, 512, 0, stream>>>(bsum, nbN);
  scanC_dinv_kernel<<<nbN, 256, 0, stream>>>(rowptr, bsum, cnt, dinv, N, E);
  fill_kernel<<<nbE, 256, 0, stream>>>(srcp, dstp, rowptr, cnt, dinv, erec, E);

  wsplit_kernel<<<(160 * 128 + 128 * 128 + 255) / 256, 256, 0, stream>>>(
      W1, W2, w1hi, w1lo, w2hi, w2lo);

  gemm_mfma_kernel<<<(N + 127) / 128, 512, 0, stream>>>(x, emb, drnl, w1hi, w1lo, hwb, N, 160);
  agg_kernel<<<(N * 64 + 255) / 256, 256, 0, stream>>>((const unsigned*)hwb, rowptr, erec, dinv, b1, z, N);
  gemm_mfma_kernel<<<(N + 127) / 128, 512, 0, stream>>>(z, emb, drnl, w2hi, w2lo, hwb, N, 128);
  agg_kernel<<<(N * 64 + 255) / 256, 256, 0, stream>>>((const unsigned*)hwb, rowptr, erec, dinv, b2, z, N);
  final_kernel<<<G, 128, 0, stream>>>(z, tloc, ptr, Wm1, bm1, Wm2, bm2, out, NPG);
}